// Round 1
// baseline (1039.183 us; speedup 1.0000x reference)
//
#include <hip/hip_runtime.h>

#define BATCH 65536
#define NF 16

typedef unsigned short u16;
typedef __bf16 bf16;
typedef bf16 bf16x4 __attribute__((ext_vector_type(4)));
typedef bf16 bf16x8 __attribute__((ext_vector_type(8)));
typedef float f32x4 __attribute__((ext_vector_type(4)));

__device__ __forceinline__ float tanh_fast(float v) {
  // tanh(v) = 1 - 2/(exp(2v)+1); rcp(inf)=0 makes the +/-large cases exact
  float e = __expf(v + v);
  return 1.0f - 2.0f * __builtin_amdgcn_rcpf(e + 1.0f);
}

__device__ __forceinline__ bf16x4 cvt4(f32x4 v) {
  // plain casts -> compiler emits packed bf16 converts (RNE)
  return bf16x4{(bf16)v[0], (bf16)v[1], (bf16)v[2], (bf16)v[3]};
}

// Swapped-operand layout: D[feat][batch] = mfma(A=W_frag, B=u_frag).
//  - u lives in LDS as [buf][batch=64][feat pad 136] bf16 (row stride 272 B,
//    16B-multiple so ds_read_b128 stays aligned). Double-buffered: each geval
//    reads U[RD], writes U[WR], ONE barrier per geval.
//  - Wave w owns feature tiles {2w, 2w+1}; loops over 4 batch tiles.
//  - Thread's 4 accum values = 4 consecutive features for one batch column:
//    LDS writeback is one ds_write_b64 (bf16x4), out-store is one dwordx4.
//  - Features 100..127 carry zero weights/bias -> u pad stays exactly 0.
__global__ __launch_bounds__(256, 3) void node_kernel(
    const float* __restrict__ x,
    const float* __restrict__ W0, const float* __restrict__ b0,
    const float* __restrict__ W1, const float* __restrict__ b1,
    const float* __restrict__ Wode, const float* __restrict__ bode,
    float* __restrict__ out)
{
  __shared__ __align__(16) u16 U[2][64][136];

  const int tid  = threadIdx.x;
  const int lane = tid & 63;
  const int w    = tid >> 6;   // wave 0..3
  const int col  = lane & 15;  // batch column within a 16-tile
  const int quad = lane >> 4;
  const int rowBase = blockIdx.x * 64;

  const float dt  = 1.0f / 15.0f;
  const float dt3 = dt / 3.0f;
  const float e8  = dt * 0.125f;
  const float q8  = dt * dt * 0.125f;

  // this thread's feature base (output rows of D) per n2
  int fb[2];
  fb[0] = (w * 2) * 16 + quad * 4;
  fb[1] = fb[0] + 16;

  // global out element base per n2 (add bt*25600 + t*100)
  int ob[2];
  ob[0] = (rowBase + col) * (NF * 100) + fb[0];
  ob[1] = (rowBase + col) * (NF * 100) + fb[1];

  // ---- W_ode A-fragments + bias vectors (persistent registers) ----
  bf16x8 bfo[2][4];
  f32x4  bvo[2];
#pragma unroll
  for (int n2 = 0; n2 < 2; ++n2) {
    const int n = (w * 2 + n2) * 16 + col;   // A row index = lane&15 within tile
    const float* Wr = Wode + n * 100;
#pragma unroll
    for (int kc = 0; kc < 4; ++kc)
#pragma unroll
      for (int j = 0; j < 8; ++j) {
        const int k = kc * 32 + quad * 8 + j;
        bfo[n2][kc][j] = (n < 100 && k < 100) ? (bf16)Wr[k] : (bf16)0.0f;
      }
#pragma unroll
    for (int r = 0; r < 4; ++r) {
      const int f = fb[n2] + r;
      bvo[n2][r] = (f < 100) ? bode[f] : 0.0f;
    }
  }

  // ---- stage x into U[0]: [batch][feat] bf16, pad features 100..127 = 0 ----
#pragma unroll 1
  for (int i = tid; i < 2048; i += 256) {
    const int b  = i >> 5;
    const int f4 = i & 31;
    f32x4 v = {0.0f, 0.0f, 0.0f, 0.0f};
    if (f4 < 25) v = *(const f32x4*)&x[(rowBase + b) * 100 + f4 * 4];
    *(bf16x4*)&U[0][b][f4 * 4] = cvt4(v);
  }

  f32x4 y0a[4][2], y1a[4][2];

  // ---- init: y0 = x@W0^T + b0 ; y1 = x@W1^T + b1 ; seed U[1]=y0 ; out t=0 ----
  {
    bf16x8 bf0[2][4], bf1[2][4];
    f32x4  bv0[2], bv1[2];
#pragma unroll
    for (int n2 = 0; n2 < 2; ++n2) {
      const int n = (w * 2 + n2) * 16 + col;
      const float* W0r = W0 + n * 100;
      const float* W1r = W1 + n * 100;
#pragma unroll
      for (int kc = 0; kc < 4; ++kc)
#pragma unroll
        for (int j = 0; j < 8; ++j) {
          const int k = kc * 32 + quad * 8 + j;
          const bool ok = (n < 100 && k < 100);
          bf0[n2][kc][j] = ok ? (bf16)W0r[k] : (bf16)0.0f;
          bf1[n2][kc][j] = ok ? (bf16)W1r[k] : (bf16)0.0f;
        }
#pragma unroll
      for (int r = 0; r < 4; ++r) {
        const int f = fb[n2] + r;
        bv0[n2][r] = (f < 100) ? b0[f] : 0.0f;
        bv1[n2][r] = (f < 100) ? b1[f] : 0.0f;
      }
    }

    __syncthreads();   // x staging visible

#pragma unroll
    for (int bt = 0; bt < 4; ++bt) {
      const int rbase = (bt * 16 + col) * 136;
      bf16x8 uf[4];
#pragma unroll
      for (int kc = 0; kc < 4; ++kc)
        uf[kc] = *(const bf16x8*)&U[0][0][rbase + kc * 32 + quad * 8];
#pragma unroll
      for (int n2 = 0; n2 < 2; ++n2) {
        f32x4 a0 = bv0[n2], a1 = bv1[n2];
#pragma unroll
        for (int kc = 0; kc < 4; ++kc) {
          a0 = __builtin_amdgcn_mfma_f32_16x16x32_bf16(bf0[n2][kc], uf[kc], a0, 0, 0, 0);
          a1 = __builtin_amdgcn_mfma_f32_16x16x32_bf16(bf1[n2][kc], uf[kc], a1, 0, 0, 0);
        }
        y0a[bt][n2] = a0;
        y1a[bt][n2] = a1;
        *(bf16x4*)&U[1][0][rbase + fb[n2]] = cvt4(a0);      // seed u = y0
        if (fb[n2] < 100)
          *(f32x4*)&out[ob[n2] + bt * 25600] = a1;          // out[:,0,:] = s1
      }
    }
  }
  __syncthreads();   // seed visible

  f32x4 k1[4][2], k2[4][2];

  // One geval: read u from U[RD], MFMA, tanh, FOLD (sets uw), write u' to U[WR],
  // single barrier. Buffer parity is compile-time (4 gevals/step, even).
#define GEVAL(RD, WR, FOLD) do {                                                \
    _Pragma("unroll")                                                           \
    for (int bt = 0; bt < 4; ++bt) {                                            \
      const int rbase = (bt * 16 + col) * 136;                                  \
      bf16x8 uf[4];                                                             \
      _Pragma("unroll")                                                         \
      for (int kc = 0; kc < 4; ++kc)                                            \
        uf[kc] = *(const bf16x8*)&U[RD][0][rbase + kc * 32 + quad * 8];         \
      _Pragma("unroll")                                                         \
      for (int n2 = 0; n2 < 2; ++n2) {                                          \
        f32x4 acc = bvo[n2];                                                    \
        _Pragma("unroll")                                                       \
        for (int kc = 0; kc < 4; ++kc)                                          \
          acc = __builtin_amdgcn_mfma_f32_16x16x32_bf16(bfo[n2][kc], uf[kc],    \
                                                        acc, 0, 0, 0);          \
        f32x4 z;                                                                \
        _Pragma("unroll")                                                       \
        for (int r = 0; r < 4; ++r) z[r] = tanh_fast(acc[r]);                   \
        f32x4 uw;                                                               \
        FOLD;                                                                   \
        *(bf16x4*)&U[WR][0][rbase + fb[n2]] = cvt4(uw);                         \
      }                                                                         \
    }                                                                           \
    __syncthreads();                                                            \
  } while (0)

#pragma unroll 1
  for (int t = 1; t < NF; ++t) {
    const int ot = t * 100;

    // g1: k1 = g(y0); u2 = y0 + dt/3*k1
    GEVAL(1, 0, {
      k1[bt][n2] = z;
      uw = y0a[bt][n2] + dt3 * z;
    });

    // g2: k2 = g(u2); u3 = y0 + dt*k2 - dt/3*k1
    GEVAL(0, 1, {
      k2[bt][n2] = z;
      uw = y0a[bt][n2] + dt * z - dt3 * k1[bt][n2];
    });

    // g3: k3 = g(u3); u4 = y0 + dt*(k1-k2+k3); fold y1, partial-fold y0; out[t]
    GEVAL(1, 0, {
      const f32x4 a   = k1[bt][n2];
      const f32x4 b2  = k2[bt][n2];
      const f32x4 y0v = y0a[bt][n2];
      uw = y0v + dt * (a - b2 + z);
      const f32x4 ny1 = y1a[bt][n2] + dt * y0v + q8 * (a + 2.0f * b2 + z);
      y1a[bt][n2] = ny1;
      y0a[bt][n2] = y0v + e8 * (a + 3.0f * (b2 + z));
      if (fb[n2] < 100)
        *(f32x4*)&out[ob[n2] + bt * 25600 + ot] = ny1;
    });

    // g4: k4 = g(u4); y0 += dt/8*k4; write y0 as next step's u
    GEVAL(0, 1, {
      const f32x4 y0v = y0a[bt][n2] + e8 * z;
      y0a[bt][n2] = y0v;
      uw = y0v;
    });
  }
#undef GEVAL
}

extern "C" void kernel_launch(void* const* d_in, const int* in_sizes, int n_in,
                              void* d_out, int out_size, void* d_ws, size_t ws_size,
                              hipStream_t stream) {
  (void)in_sizes; (void)n_in; (void)out_size; (void)d_ws; (void)ws_size;
  const float* x    = (const float*)d_in[0];
  const float* W0   = (const float*)d_in[1];
  const float* b0   = (const float*)d_in[2];
  const float* W1   = (const float*)d_in[3];
  const float* b1   = (const float*)d_in[4];
  const float* Wode = (const float*)d_in[5];
  const float* bode = (const float*)d_in[6];
  float* out = (float*)d_out;

  dim3 grid(BATCH / 64), block(256);
  hipLaunchKernelGGL(node_kernel, grid, block, 0, stream,
                     x, W0, b0, W1, b1, Wode, bode, out);
}

// Round 3
// 692.715 us; speedup vs baseline: 1.5002x; 1.5002x over previous
//
#include <hip/hip_runtime.h>

#define BATCH 65536
#define NF 16

typedef __bf16 bf16;
typedef bf16 bf16x8 __attribute__((ext_vector_type(8)));
typedef float f32x4 __attribute__((ext_vector_type(4)));

__device__ __forceinline__ float tanh_fast(float v) {
  // tanh(v) = 1 - 2/(exp(2v)+1); exp(2v) = exp2(v * 2/ln2); rcp(inf)=0 -> exact at +/-large
  float e = exp2f(v * 2.8853900817779268f);
  return 1.0f - 2.0f * __builtin_amdgcn_rcpf(e + 1.0f);
}

// Proven orientation: D[batch][feat] = mfma(A=u_frag, B=W_frag).
//  - u in LDS, MFMA A-fragment layout, element (row r64, col c) at
//      idx8 = (c>>3)*65 + r64   (pad 64->65), elem = idx8*8 + (c&7)
//    DOUBLE-BUFFERED: each geval reads Au[RD], writes Au[WR], ONE barrier.
//  - 8 waves (512 thr): wave w owns feature tile [16w,16w+16); loops 4 row-tiles.
//  - Out stores: scalar f32, lanes cover 16 consecutive features x 4 rows
//    -> full 64B segments per instruction (clean write path, no write-allocate).
__global__ __launch_bounds__(512, 4) void node_kernel(
    const float* __restrict__ x,
    const float* __restrict__ W0, const float* __restrict__ b0,
    const float* __restrict__ W1, const float* __restrict__ b1,
    const float* __restrict__ Wode, const float* __restrict__ bode,
    float* __restrict__ out)
{
  __shared__ __align__(16) bf16 Au[2][8320];

  const int tid  = threadIdx.x;
  const int lane = tid & 63;
  const int w    = tid >> 6;   // wave 0..7
  const int col  = lane & 15;
  const int quad = lane >> 4;
  const int rowBase = blockIdx.x * 64;

  const float dt  = 1.0f / 15.0f;
  const float dt3 = dt / 3.0f;
  const float e8  = dt * 0.125f;
  const float q8  = dt * dt * 0.125f;

  const int  n    = w * 16 + col;                       // this lane's feature (D col)
  const bool nok  = (n < 100);
  const int  abase = ((n >> 3) * 65 + quad * 4) * 8 + (n & 7);  // LDS elem base (scatter)
  const int  obase = (rowBase + quad * 4) * (NF * 100) + n;     // out elem base

  // ---- W_ode B-fragments + bias (persistent registers) ----
  bf16x8 bfo[4];
  const float biaso = nok ? bode[n] : 0.0f;
#pragma unroll
  for (int kc = 0; kc < 4; ++kc)
#pragma unroll
    for (int j = 0; j < 8; ++j) {
      const int k = kc * 32 + quad * 8 + j;
      bfo[kc][j] = (nok && k < 100) ? (bf16)Wode[n * 100 + k] : (bf16)0.0f;
    }

  // ---- stage x into Au[0] (coalesced fp32 reads -> bf16 A-layout), pad=0 ----
#pragma unroll 1
  for (int i = tid; i < 8192; i += 512) {
    const int r64 = i >> 7;
    const int c   = i & 127;
    const float v = (c < 100) ? x[(rowBase + r64) * 100 + c] : 0.0f;
    Au[0][((c >> 3) * 65 + r64) * 8 + (c & 7)] = (bf16)v;
  }

  f32x4 y0a[4], y1a[4], k1[4], k2[4];

  // ---- init: y0 = x@W0^T + b0 ; y1 = x@W1^T + b1 ; seed Au[1]=y0 ; out t=0 ----
  {
    bf16x8 bf0[4], bf1[4];
    const float bias0 = nok ? b0[n] : 0.0f;
    const float bias1 = nok ? b1[n] : 0.0f;
#pragma unroll
    for (int kc = 0; kc < 4; ++kc)
#pragma unroll
      for (int j = 0; j < 8; ++j) {
        const int k = kc * 32 + quad * 8 + j;
        const bool ok = (nok && k < 100);
        bf0[kc][j] = ok ? (bf16)W0[n * 100 + k] : (bf16)0.0f;
        bf1[kc][j] = ok ? (bf16)W1[n * 100 + k] : (bf16)0.0f;
      }

    __syncthreads();   // x staging visible

#pragma unroll
    for (int rt = 0; rt < 4; ++rt) {
      bf16x8 af[4];
#pragma unroll
      for (int kc = 0; kc < 4; ++kc)
        af[kc] = *(const bf16x8*)&Au[0][((kc * 4 + quad) * 65 + rt * 16 + col) * 8];
      f32x4 a0 = { bias0, bias0, bias0, bias0 };
      f32x4 a1 = { bias1, bias1, bias1, bias1 };
#pragma unroll
      for (int kc = 0; kc < 4; ++kc) {
        a0 = __builtin_amdgcn_mfma_f32_16x16x32_bf16(af[kc], bf0[kc], a0, 0, 0, 0);
        a1 = __builtin_amdgcn_mfma_f32_16x16x32_bf16(af[kc], bf1[kc], a1, 0, 0, 0);
      }
      y0a[rt] = a0;
      y1a[rt] = a1;
#pragma unroll
      for (int r = 0; r < 4; ++r) {
        Au[1][abase + rt * 128 + r * 8] = (bf16)a0[r];   // seed u = y0 (other buffer)
        if (nok) out[obase + rt * 25600 + r * 1600] = a1[r];
      }
    }
  }
  __syncthreads();   // seed visible

  // One geval: read u-frags from Au[RD], MFMA, tanh, FOLD (sets uw, may store out),
  // write u' to Au[WR]. Single barrier; buffer parity compile-time (4 gevals/step).
#define GEVAL(RD, WR, ...) do {                                                 \
    _Pragma("unroll")                                                           \
    for (int rt = 0; rt < 4; ++rt) {                                            \
      bf16x8 af[4];                                                             \
      _Pragma("unroll")                                                         \
      for (int kc = 0; kc < 4; ++kc)                                            \
        af[kc] = *(const bf16x8*)&Au[RD][((kc * 4 + quad) * 65 + rt * 16 + col) * 8]; \
      f32x4 acc = { biaso, biaso, biaso, biaso };                               \
      _Pragma("unroll")                                                         \
      for (int kc = 0; kc < 4; ++kc)                                            \
        acc = __builtin_amdgcn_mfma_f32_16x16x32_bf16(af[kc], bfo[kc], acc, 0, 0, 0); \
      f32x4 z;                                                                  \
      _Pragma("unroll")                                                         \
      for (int r = 0; r < 4; ++r) z[r] = tanh_fast(acc[r]);                     \
      f32x4 uw;                                                                 \
      __VA_ARGS__;                                                              \
      _Pragma("unroll")                                                         \
      for (int r = 0; r < 4; ++r)                                               \
        Au[WR][abase + rt * 128 + r * 8] = (bf16)uw[r];                         \
    }                                                                           \
    __syncthreads();                                                            \
  } while (0)

#pragma unroll 1
  for (int t = 1; t < NF; ++t) {
    const int ot = t * 100;

    // g1: k1 = g(y0); u2 = y0 + dt/3*k1
    GEVAL(1, 0, {
      k1[rt] = z;
      uw = y0a[rt] + dt3 * z;
    });

    // g2: k2 = g(u2); u3 = y0 + dt*k2 - dt/3*k1
    GEVAL(0, 1, {
      k2[rt] = z;
      uw = y0a[rt] + dt * z - dt3 * k1[rt];
    });

    // g3: k3 = g(u3); u4 = y0 + dt*(k1-k2+k3); fold y1, partial-fold y0; out[t]
    GEVAL(1, 0, {
      const f32x4 a   = k1[rt];
      const f32x4 b2  = k2[rt];
      const f32x4 y0v = y0a[rt];
      uw = y0v + dt * (a - b2 + z);
      const f32x4 ny1 = y1a[rt] + dt * y0v + q8 * (a + 2.0f * b2 + z);
      y1a[rt] = ny1;
      y0a[rt] = y0v + e8 * (a + 3.0f * (b2 + z));
      _Pragma("unroll")
      for (int r = 0; r < 4; ++r)
        if (nok) out[obase + rt * 25600 + r * 1600 + ot] = ny1[r];
    });

    // g4: k4 = g(u4); y0 += dt/8*k4; write y0 as next step's u
    GEVAL(0, 1, {
      const f32x4 y0v = y0a[rt] + e8 * z;
      y0a[rt] = y0v;
      uw = y0v;
    });
  }
#undef GEVAL
}

extern "C" void kernel_launch(void* const* d_in, const int* in_sizes, int n_in,
                              void* d_out, int out_size, void* d_ws, size_t ws_size,
                              hipStream_t stream) {
  (void)in_sizes; (void)n_in; (void)out_size; (void)d_ws; (void)ws_size;
  const float* x    = (const float*)d_in[0];
  const float* W0   = (const float*)d_in[1];
  const float* b0   = (const float*)d_in[2];
  const float* W1   = (const float*)d_in[3];
  const float* b1   = (const float*)d_in[4];
  const float* Wode = (const float*)d_in[5];
  const float* bode = (const float*)d_in[6];
  float* out = (float*)d_out;

  dim3 grid(BATCH / 64), block(512);
  hipLaunchKernelGGL(node_kernel, grid, block, 0, stream,
                     x, W0, b0, W1, b1, Wode, bode, out);
}